// Round 2
// baseline (688.076 us; speedup 1.0000x reference)
//
#include <hip/hip_runtime.h>
#include <hip/hip_bf16.h>

#define BS 1024
#define TS 64
#define HID 64
#define NG 256       // 4*HID
#define BPB 4        // batch elements per block
#define NBLK (BS/BPB)

__device__ __forceinline__ float sigf(float x){ return 1.f/(1.f+expf(-x)); }
__device__ __forceinline__ float lrelu(float v){ return v>=0.f ? v : 0.1f*v; }
__device__ __forceinline__ float dot4(float4 a, float4 b){
  return a.x*b.x + a.y*b.y + a.z*b.z + a.w*b.w;
}

// ---------------- Kernel A: batch-independent precompute ----------------
// Computes: ws_wcomb[64*64] = Wmix[:,64:] @ Wof
//           ws_mbias[64*64] : per-step mix bias  (teom LSTM folded in)
__global__ __launch_bounds__(256) void precompute_kernel(
    const float* __restrict__ Whh_t, const float* __restrict__ bih_t,
    const float* __restrict__ bhh_t,
    const float* __restrict__ Wof,  const float* __restrict__ bof,
    const float* __restrict__ Wtf,  const float* __restrict__ btf,
    const float* __restrict__ Wmix, const float* __restrict__ bmix,
    float* __restrict__ ws_wcomb, float* __restrict__ ws_mbias)
{
  __shared__ __align__(16) float4 sWtfT[16*64];   // Wtf transposed-packed
  __shared__ __align__(16) float4 sWm1T[16*64];   // Wmix[:, :64] transposed-packed
  __shared__ float sWof[64*64];
  __shared__ float sBof[64];
  __shared__ __align__(16) float sH[64];
  __shared__ __align__(16) float sTs[64];
  __shared__ float sG[256];

  const int t = threadIdx.x;

  // Whh_t row t in registers
  float4 wv[16];
#pragma unroll
  for (int j4=0;j4<16;++j4) wv[j4] = reinterpret_cast<const float4*>(Whh_t + t*64)[j4];
  const float btr = bih_t[t] + bhh_t[t];

  for (int i=t;i<64*64;i+=256) sWof[i] = Wof[i];
  if (t<64){
    sBof[t] = bof[t];
    sH[t]   = 0.f;
#pragma unroll
    for (int j4=0;j4<16;++j4){
      sWtfT[j4*64+t] = reinterpret_cast<const float4*>(Wtf  + t*64 )[j4];
      sWm1T[j4*64+t] = reinterpret_cast<const float4*>(Wmix + t*128)[j4];
    }
  }
  __syncthreads();

  float cmr = 0.f, btfr = 0.f;
  if (t<64){
    btfr = btf[t];
    float acc = bmix[t];
    for (int k=0;k<64;++k) acc += Wmix[t*128+64+k]*sBof[k];
    cmr = acc;  // Wmix2 @ bof + bmix
  }
  // Wcomb = Wmix2 @ Wof   (16 outputs/thread, coalesced writes)
  for (int i=0;i<16;++i){
    int o = i*256+t;
    int r = o>>6, j = o&63;
    float acc = 0.f;
    for (int k=0;k<64;++k) acc += Wmix[r*128+64+k]*sWof[k*64+j];
    ws_wcomb[o] = acc;
  }

  float c_reg = 0.f;
  const float4* sH4  = reinterpret_cast<const float4*>(sH);
  const float4* sTs4 = reinterpret_cast<const float4*>(sTs);

  for (int s=0; s<TS; ++s){
    // gates (z input = 0): g = Whh_t @ h + b_t
    float acc = btr;
#pragma unroll
    for (int j4=0;j4<16;++j4) acc += dot4(wv[j4], sH4[j4]);
    sG[t] = acc;
    __syncthreads();
    if (t<64){
      float ig = sigf(sG[t]);
      float fg = sigf(sG[64+t]);
      float gg = tanhf(sG[128+t]);
      float og = sigf(sG[192+t]);
      c_reg = fg*c_reg + ig*gg;
      sH[t] = og*tanhf(c_reg);
    }
    __syncthreads();
    if (t<64){
      float a2 = btfr;
#pragma unroll
      for (int j4=0;j4<16;++j4) a2 += dot4(sWtfT[j4*64+t], sH4[j4]);
      sTs[t] = a2;
    }
    __syncthreads();
    if (t<64){
      float a3 = cmr;
#pragma unroll
      for (int j4=0;j4<16;++j4) a3 += dot4(sWm1T[j4*64+t], sTs4[j4]);
      ws_mbias[s*64+t] = a3;
    }
    __syncthreads();
  }
}

// ---------------- Kernel B: per-batch recurrence ----------------
__global__ __launch_bounds__(256) void main_kernel(
    const float* __restrict__ obsv,
    const float* __restrict__ Wih_o, const float* __restrict__ Whh_o,
    const float* __restrict__ bih_o, const float* __restrict__ bhh_o,
    const float* __restrict__ W1, const float* __restrict__ b1,
    const float* __restrict__ W2, const float* __restrict__ b2,
    const float* __restrict__ W3, const float* __restrict__ b3,
    const float* __restrict__ ws_wcomb, const float* __restrict__ ws_mbias,
    float* __restrict__ out)
{
  __shared__ __align__(16) float4 sWc[16*64];   // Wcomb transposed-packed
  __shared__ __align__(16) float4 sW1[16*32];
  __shared__ __align__(16) float4 sW2[8*32];
  __shared__ float sW3[64];
  __shared__ __align__(16) float sMb[TS*64];
  __shared__ float sG[BPB*NG];
  __shared__ __align__(16) float sH[BPB*HID];
  __shared__ __align__(16) float sM[BPB*64];
  __shared__ __align__(16) float sA1[BPB*32];
  __shared__ float sA2[BPB*32];
  __shared__ float sObs[BPB*16];
  __shared__ float sBuf[BPB*6];   // [b][slot(3)][r(2)]
  __shared__ float sB1[32], sB2[32], sB3[2];

  const int t   = threadIdx.x;
  const int blk = blockIdx.x;
  const int b0  = blk*BPB;

  // zero the c_out output region (fp32 zeros): floats [BS*TS*2, BS*TS*3)
  out[BS*TS*2 + blk*256 + t] = 0.f;

  // Whh_o row t in registers; Wih / bias folded
  float4 wv[16];
#pragma unroll
  for (int j4=0;j4<16;++j4) wv[j4] = reinterpret_cast<const float4*>(Whh_o + t*64)[j4];
  const float wi0  = Wih_o[t*2];
  const float wi1  = Wih_o[t*2+1];
  const float b_or = bih_o[t] + bhh_o[t];

  // ---- staging ----
  if (t < 64){
#pragma unroll
    for (int j4=0;j4<16;++j4)
      sWc[j4*64+t] = reinterpret_cast<const float4*>(ws_wcomb + t*64)[j4];
    sW3[t] = W3[t];
  } else if (t < 96){
    const int rr = t-64;
#pragma unroll
    for (int j4=0;j4<16;++j4)
      sW1[j4*32+rr] = reinterpret_cast<const float4*>(W1 + rr*64)[j4];
    sB1[rr] = b1[rr];
  } else if (t < 128){
    const int rr = t-96;
#pragma unroll
    for (int j4=0;j4<8;++j4)
      sW2[j4*32+rr] = reinterpret_cast<const float4*>(W2 + rr*32)[j4];
    sB2[rr] = b2[rr];
  }
  if (t<2) sB3[t] = b3[t];
#pragma unroll
  for (int i=0;i<4;++i)
    reinterpret_cast<float4*>(sMb)[t*4+i] = reinterpret_cast<const float4*>(ws_mbias)[t*4+i];
  if (t<64) sObs[t] = obsv[b0*16 + t];
  sH[t] = 0.f;
  __syncthreads();
  if (t<24){ int b=t/6, i=t%6; sBuf[t] = sObs[b*16+10+i]; }  // obsv[:,5:8,:]
  __syncthreads();

  float c_reg = 0.f;
  const int eb = t>>6, ek = t&63;     // elementwise mapping
  const int mb = t>>6, mr = t&63;     // mix mapping (wave-per-batch)
  const float4* sH4  = reinterpret_cast<const float4*>(sH);
  const float4* sM4  = reinterpret_cast<const float4*>(sM);
  const float4* sA14 = reinterpret_cast<const float4*>(sA1);

  // ---- warmup: 8 obsv LSTM steps ----
  for (int s=0;s<8;++s){
    float acc[BPB];
#pragma unroll
    for (int b=0;b<BPB;++b)
      acc[b] = b_or + wi0*sObs[b*16+2*s] + wi1*sObs[b*16+2*s+1];
#pragma unroll
    for (int j4=0;j4<16;++j4){
      float4 w = wv[j4];
#pragma unroll
      for (int b=0;b<BPB;++b) acc[b] += dot4(w, sH4[b*16+j4]);
    }
#pragma unroll
    for (int b=0;b<BPB;++b) sG[b*NG + t] = acc[b];
    __syncthreads();
    {
      float ig = sigf(sG[eb*NG+ek]);
      float fg = sigf(sG[eb*NG+64+ek]);
      float gg = tanhf(sG[eb*NG+128+ek]);
      float og = sigf(sG[eb*NG+192+ek]);
      c_reg = fg*c_reg + ig*gg;
      sH[eb*64+ek] = og*tanhf(c_reg);
    }
    __syncthreads();
  }

  // ---- main loop: 64 output steps ----
  for (int step=0; step<TS; ++step){
    if (step>0){
      float acc[BPB];
#pragma unroll
      for (int b=0;b<BPB;++b)
        acc[b] = b_or + wi0*sBuf[b*6+4] + wi1*sBuf[b*6+5];   // x = buf[:,-1] = y_{t-1}
#pragma unroll
      for (int j4=0;j4<16;++j4){
        float4 w = wv[j4];
#pragma unroll
        for (int b=0;b<BPB;++b) acc[b] += dot4(w, sH4[b*16+j4]);
      }
#pragma unroll
      for (int b=0;b<BPB;++b) sG[b*NG+t] = acc[b];
      __syncthreads();
      {
        float ig = sigf(sG[eb*NG+ek]);
        float fg = sigf(sG[eb*NG+64+ek]);
        float gg = tanhf(sG[eb*NG+128+ek]);
        float og = sigf(sG[eb*NG+192+ek]);
        c_reg = fg*c_reg + ig*gg;
        sH[eb*64+ek] = og*tanhf(c_reg);
      }
      __syncthreads();
    }
    // mix: m = Wcomb @ h + mbias[step]
    {
      float acc = sMb[step*64+mr];
#pragma unroll
      for (int j4=0;j4<16;++j4) acc += dot4(sWc[j4*64+mr], sH4[mb*16+j4]);
      sM[mb*64+mr] = acc;
    }
    __syncthreads();
    if (mr<32){
      float acc = sB1[mr];
#pragma unroll
      for (int j4=0;j4<16;++j4) acc += dot4(sW1[j4*32+mr], sM4[mb*16+j4]);
      sA1[mb*32+mr] = lrelu(acc);
    }
    __syncthreads();
    if (mr<32){
      float acc = sB2[mr];
#pragma unroll
      for (int j4=0;j4<8;++j4) acc += dot4(sW2[j4*32+mr], sA14[mb*8+j4]);
      sA2[mb*32+mr] = lrelu(acc);
    }
    __syncthreads();
    if (mr<2){
      float acc = sB3[mr];
#pragma unroll
      for (int j=0;j<32;++j) acc += sW3[mr*32+j]*sA2[mb*32+j];
      float bl0 = sBuf[mb*6+0+mr];
      float bl1 = sBuf[mb*6+2+mr];
      float bl2 = sBuf[mb*6+4+mr];
      float y = acc + bl2 + (bl2-bl0)*0.5f;
      sBuf[mb*6+0+mr] = bl1;
      sBuf[mb*6+2+mr] = bl2;
      sBuf[mb*6+4+mr] = y;
      out[((size_t)(b0+mb)*TS + step)*2 + mr] = y;
    }
    __syncthreads();
  }
}

extern "C" void kernel_launch(void* const* d_in, const int* in_sizes, int n_in,
                              void* d_out, int out_size, void* d_ws, size_t ws_size,
                              hipStream_t stream)
{
  const float* obsv  = (const float*)d_in[0];
  // d_in[1] = teom : values never used by the reference (input is zeros)
  const float* Wih_o = (const float*)d_in[2];
  const float* Whh_o = (const float*)d_in[3];
  const float* bih_o = (const float*)d_in[4];
  const float* bhh_o = (const float*)d_in[5];
  // d_in[6] = Wih_t : multiplies zeros, unused
  const float* Whh_t = (const float*)d_in[7];
  const float* bih_t = (const float*)d_in[8];
  const float* bhh_t = (const float*)d_in[9];
  const float* Wof   = (const float*)d_in[10];
  const float* bof   = (const float*)d_in[11];
  const float* Wtf   = (const float*)d_in[12];
  const float* btf   = (const float*)d_in[13];
  const float* Wmix  = (const float*)d_in[14];
  const float* bmix  = (const float*)d_in[15];
  const float* W1    = (const float*)d_in[16];
  const float* b1    = (const float*)d_in[17];
  const float* W2    = (const float*)d_in[18];
  const float* b2    = (const float*)d_in[19];
  const float* W3    = (const float*)d_in[20];
  const float* b3    = (const float*)d_in[21];

  float* wsf = (float*)d_ws;          // [0,4096): Wcomb   [4096,8192): mbias

  precompute_kernel<<<1,256,0,stream>>>(Whh_t,bih_t,bhh_t,Wof,bof,Wtf,btf,
                                        Wmix,bmix, wsf, wsf+4096);
  main_kernel<<<NBLK,256,0,stream>>>(obsv,Wih_o,Whh_o,bih_o,bhh_o,
                                     W1,b1,W2,b2,W3,b3,
                                     wsf, wsf+4096,
                                     (float*)d_out);
}